// Round 6
// baseline (228.771 us; speedup 1.0000x reference)
//
#include <hip/hip_runtime.h>
#include <math.h>

#define T_IN 2048
#define TP   2051   // T+3 conv output length
#define F    256
#define H    384
#define BK   16     // k2 K-tile
#define BT2  32     // k2 t-tile
#define NT2  65     // ceil(TP/32) t-tiles in k2
#define NCS  257    // 8-t chunks (scan length)
#define NC4  513    // k3 chunks of 4 (2 per 8-t cs chunk)

__device__ __forceinline__ float logsig(float z) {
    return (z >= 0.0f) ? -log1pf(__expf(-z)) : z - log1pf(__expf(z));
}

union F4 { float4 v; float f[4]; };

// ---------- D1: conv (blocks 0..512) + q/o GEMV (513..608) + zero (609) ----------
__global__ __launch_bounds__(256) void k1_front(const float* __restrict__ x,
        const float* __restrict__ cw, const float* __restrict__ cb,
        const float* __restrict__ Wq, const float* __restrict__ bq,
        const float* __restrict__ Wo, const float* __restrict__ bo,
        float* __restrict__ xp, float* __restrict__ q, float* __restrict__ o,
        float* __restrict__ zf) {
    int bid = blockIdx.x;
    int tid = threadIdx.x;
    if (bid < 513) {
        int t = bid * 4 + (tid >> 6);
        int f4 = tid & 63;
        if (t >= TP) return;
        float w[4] = {cw[0], cw[1], cw[2], cw[3]};
        float b = cb[0];
        float4 acc = {b, b, b, b};
        int i0 = t - 3;
        const float4* x4 = (const float4*)x;
        #pragma unroll
        for (int j = 0; j < 4; ++j) {
            int tt = i0 + j;
            if (tt >= 0 && tt < T_IN) {
                float4 xv = x4[tt * 64 + f4];
                acc.x = fmaf(w[j], xv.x, acc.x);
                acc.y = fmaf(w[j], xv.y, acc.y);
                acc.z = fmaf(w[j], xv.z, acc.z);
                acc.w = fmaf(w[j], xv.w, acc.w);
            }
        }
        ((float4*)xp)[t * 64 + f4] = acc;
    } else if (bid < 609) {
        int lane = tid & 63;
        int row = (bid - 513) * 4 + (tid >> 6);
        float w0 = cw[0], b = cb[0];
        float4 xr = ((const float4*)x)[2047 * 64 + lane];
        float4 xv;
        xv.x = fmaf(w0, xr.x, b);
        xv.y = fmaf(w0, xr.y, b);
        xv.z = fmaf(w0, xr.z, b);
        xv.w = fmaf(w0, xr.w, b);
        float4 q4 = *(const float4*)&Wq[row * 256 + lane * 4];
        float4 o4 = *(const float4*)&Wo[row * 256 + lane * 4];
        float aq = fmaf(xv.x, q4.x, fmaf(xv.y, q4.y, fmaf(xv.z, q4.z, xv.w * q4.w)));
        float ao = fmaf(xv.x, o4.x, fmaf(xv.y, o4.y, fmaf(xv.z, o4.z, xv.w * o4.w)));
        #pragma unroll
        for (int off = 32; off; off >>= 1) {
            aq += __shfl_down(aq, off, 64);
            ao += __shfl_down(ao, off, 64);
        }
        if (lane == 0) {
            q[row] = aq + bq[row];
            o[row] = 1.0f / (1.0f + __expf(-(ao + bo[row])));
        }
    } else {
        // zero zf (256) + Gf (at 256) + ticket (at 264) + pad
        for (int i = tid; i < 272; i += 256) zf[i] = 0.0f;
    }
}

// ---------- D2: 32t x 64b x 1 matrix per block, grid (65,6,3) = 1170 blocks ----------
__global__ __launch_bounds__(256) void k2_proj(
    const float* __restrict__ xp,
    const float* __restrict__ Wk, const float* __restrict__ bk,
    const float* __restrict__ Wi, const float* __restrict__ bi,
    const float* __restrict__ Wf, const float* __restrict__ bf,
    float* __restrict__ zk, float* __restrict__ ai, float* __restrict__ lf,
    float* __restrict__ cs) {
    __shared__ float alds[2][BT2][20];    // xp tile [t][k], pad 20 (float4-aligned)
    __shared__ float wlds[2][BK][66];     // W^T [k][b]
    __shared__ float csred[8][66];
    int tid = threadIdx.x;
    int mz = blockIdx.z;
    const float* __restrict__ W    = (mz == 0) ? Wk : (mz == 1) ? Wi : Wf;
    const float* __restrict__ bias = (mz == 0) ? bk : (mz == 1) ? bi : bf;
    int t0 = blockIdx.x * BT2, b0 = blockIdx.y * 64;
    int tx = tid & 31, ty = tid >> 5;
    float2 acc[4];
    #pragma unroll
    for (int u = 0; u < 4; ++u) { acc[u].x = 0.f; acc[u].y = 0.f; }

    int wrow = tid >> 2;          // 0..63 (W row within tile)
    int wk4 = (tid & 3) * 4;      // k quad
    int grow = (b0 + wrow) * 256 + wk4;
    int atq = tid >> 2;           // 0..31 (a row within tile, tid<128 only)
    int arow = (t0 + atq) * 256 + wk4;
    bool aval = (tid < 128) && (t0 + atq < TP);

    float4 aw = {0.f, 0.f, 0.f, 0.f};
    float4 ww;
    // prologue: load tile 0
    if (aval) aw = *(const float4*)&xp[arow];
    ww = *(const float4*)&W[grow];

    for (int i = 0; i < 16; ++i) {
        int buf = i & 1;
        if (tid < 128) *(float4*)&alds[buf][atq][wk4] = aw;
        {
            F4 wu; wu.v = ww;
            #pragma unroll
            for (int j = 0; j < 4; ++j)
                wlds[buf][wk4 + j][wrow] = wu.f[j];
        }
        __syncthreads();
        if (i < 15) {
            int k0 = (i + 1) * BK;
            if (aval) aw = *(const float4*)&xp[arow + k0];
            ww = *(const float4*)&W[grow + k0];
        }
        #pragma unroll
        for (int g = 0; g < 4; ++g) {
            F4 av0, av1, av2, av3;
            av0.v = *(const float4*)&alds[buf][4 * ty + 0][4 * g];
            av1.v = *(const float4*)&alds[buf][4 * ty + 1][4 * g];
            av2.v = *(const float4*)&alds[buf][4 * ty + 2][4 * g];
            av3.v = *(const float4*)&alds[buf][4 * ty + 3][4 * g];
            #pragma unroll
            for (int j = 0; j < 4; ++j) {
                float2 w0 = *(const float2*)&wlds[buf][4 * g + j][2 * tx];
                acc[0].x = fmaf(av0.f[j], w0.x, acc[0].x);
                acc[0].y = fmaf(av0.f[j], w0.y, acc[0].y);
                acc[1].x = fmaf(av1.f[j], w0.x, acc[1].x);
                acc[1].y = fmaf(av1.f[j], w0.y, acc[1].y);
                acc[2].x = fmaf(av2.f[j], w0.x, acc[2].x);
                acc[2].y = fmaf(av2.f[j], w0.y, acc[2].y);
                acc[3].x = fmaf(av3.f[j], w0.x, acc[3].x);
                acc[3].y = fmaf(av3.f[j], w0.y, acc[3].y);
            }
        }
    }
    // epilogue: 4 t-rows per thread, one matrix
    int bA = b0 + 2 * tx;
    float2 b2 = *(const float2*)&bias[bA];
    if (mz == 0) {
        const float sc = 0.05103103630798287f;  // 1/sqrt(384)
        #pragma unroll
        for (int u = 0; u < 4; ++u) {
            int t = t0 + 4 * ty + u;
            if (t < TP) {
                float2 v;
                v.x = (acc[u].x + b2.x) * sc; v.y = (acc[u].y + b2.y) * sc;
                *(float2*)&zk[t * H + bA] = v;
            }
        }
    } else if (mz == 1) {
        #pragma unroll
        for (int u = 0; u < 4; ++u) {
            int t = t0 + 4 * ty + u;
            if (t < TP) {
                float2 v;
                v.x = acc[u].x + b2.x; v.y = acc[u].y + b2.y;
                *(float2*)&ai[t * H + bA] = v;
            }
        }
    } else {
        float2 lsum = {0.f, 0.f};
        #pragma unroll
        for (int u = 0; u < 4; ++u) {
            int t = t0 + 4 * ty + u;
            if (t < TP) {
                float2 l2;
                l2.x = logsig(acc[u].x + b2.x);
                l2.y = logsig(acc[u].y + b2.y);
                *(float2*)&lf[t * H + bA] = l2;
                lsum.x += l2.x; lsum.y += l2.y;
            }
        }
        // per-8t chunk sums: ty pair (2c, 2c+1) covers chunk c
        *(float2*)&csred[ty][2 * tx] = lsum;
        __syncthreads();
        int cl = tid >> 6;       // 0..3 local chunk
        int bb = tid & 63;
        int c = blockIdx.x * 4 + cl;
        if (c < NCS)
            cs[c * H + b0 + bb] = csred[2 * cl][bb] + csred[2 * cl + 1][bb];
    }
}

// ---------- D3: reverse exclusive scan over 257 chunk sums, grid 6x64 ----------
__global__ __launch_bounds__(64) void k3b_scan(const float* __restrict__ cs,
                                               float* __restrict__ co) {
    int b = blockIdx.x * 64 + threadIdx.x;
    float L = 0.0f;
    #pragma unroll 16
    for (int c = NCS - 1; c >= 0; --c) {
        co[c * H + b] = L;
        L += cs[c * H + b];
    }
}

// ---------- D4: chunk-4 backend, grid 513 x 384 (12 waves/CU vs 6 at chunk-8) ----------
// co is 8-granular; even blocks (lower half of an 8-chunk) add the upper half's
// lf values in the original descending order. Last block (ticket) runs the GEMV.
__global__ __launch_bounds__(384) void k3_back(
    const float* __restrict__ ai, const float* __restrict__ lf,
    const float* __restrict__ zk, const float* __restrict__ co,
    const float* __restrict__ q, const float* __restrict__ xp,
    float* __restrict__ zf, float* __restrict__ Gf,
    unsigned int* __restrict__ ticket,
    const float* __restrict__ Wv, const float* __restrict__ bv,
    const float* __restrict__ o, float* __restrict__ out) {
    __shared__ float zred[6][256];
    __shared__ float gred[6];
    __shared__ unsigned int stick;
    __shared__ float sGv;
    int tid = threadIdx.x;
    int w = tid >> 6, lane = tid & 63;
    int c4 = blockIdx.x, ts = c4 * 4;
    int c8 = c4 >> 1;
    float co0 = co[c8 * H + tid];
    if ((c4 & 1) == 0) {
        // E = ((lf[ts+7]+lf[ts+6])+lf[ts+5])+lf[ts+4], same order as old running S
        float E = 0.0f;
        #pragma unroll
        for (int j = 7; j >= 4; --j) {
            int t = ts + j;
            E += (t < TP) ? lf[t * H + tid] : 0.0f;
        }
        co0 += E;
    }
    float qb = q[tid];
    float aiv[4], lfv[4], zkv[4];
    float4 xv[4];
    #pragma unroll
    for (int u = 0; u < 4; ++u) {
        int t = ts + u;
        if (t < TP) {
            int idx = t * H + tid;
            aiv[u] = ai[idx]; lfv[u] = lf[idx]; zkv[u] = zk[idx];
            xv[u] = *(const float4*)&xp[t * 256 + lane * 4];
        } else {
            aiv[u] = -1e30f; lfv[u] = 0.f; zkv[u] = 0.f;
            xv[u].x = xv[u].y = xv[u].z = xv[u].w = 0.f;
        }
    }
    float S = 0.f, gsum = 0.f;
    float z0 = 0.f, z1 = 0.f, z2 = 0.f, z3 = 0.f;
    #pragma unroll
    for (int u = 3; u >= 0; --u) {
        float wv = __expf(aiv[u] + co0 + S) * zkv[u] * qb;
        S += lfv[u];
        float s = wv;
        s += __shfl_xor(s, 1, 64);
        s += __shfl_xor(s, 2, 64);
        s += __shfl_xor(s, 4, 64);
        s += __shfl_xor(s, 8, 64);
        s += __shfl_xor(s, 16, 64);
        s += __shfl_xor(s, 32, 64);
        gsum += s;
        z0 = fmaf(s, xv[u].x, z0);
        z1 = fmaf(s, xv[u].y, z1);
        z2 = fmaf(s, xv[u].z, z2);
        z3 = fmaf(s, xv[u].w, z3);
    }
    zred[w][lane * 4 + 0] = z0;
    zred[w][lane * 4 + 1] = z1;
    zred[w][lane * 4 + 2] = z2;
    zred[w][lane * 4 + 3] = z3;
    if (lane == 0) gred[w] = gsum;
    __syncthreads();
    if (tid < 256) {
        float s = zred[0][tid] + zred[1][tid] + zred[2][tid]
                + zred[3][tid] + zred[4][tid] + zred[5][tid];
        atomicAdd(&zf[tid], s);
    }
    if (tid == 0)
        atomicAdd(Gf, gred[0] + gred[1] + gred[2] + gred[3] + gred[4] + gred[5]);
    // ---- last-block finalize (k6) ----
    __threadfence();           // make this thread's atomics visible device-wide
    __syncthreads();           // all threads' atomics issued & drained
    if (tid == 0) {
        __threadfence();
        stick = atomicAdd(ticket, 1u);
    }
    __syncthreads();
    if (stick == NC4 - 1) {
        if (tid == 0) sGv = atomicAdd(Gf, 0.0f);   // atomic read: coherent
        __syncthreads();
        float Gv = sGv;
        float4 zv;
        zv.x = atomicAdd(&zf[lane * 4 + 0], 0.0f);
        zv.y = atomicAdd(&zf[lane * 4 + 1], 0.0f);
        zv.z = atomicAdd(&zf[lane * 4 + 2], 0.0f);
        zv.w = atomicAdd(&zf[lane * 4 + 3], 0.0f);
        #pragma unroll 4
        for (int r = 0; r < 64; ++r) {
            int row = w * 64 + r;
            float4 wv = *(const float4*)&Wv[row * 256 + lane * 4];
            float acc = fmaf(zv.x, wv.x, fmaf(zv.y, wv.y, fmaf(zv.z, wv.z, zv.w * wv.w)));
            #pragma unroll
            for (int off = 32; off; off >>= 1) acc += __shfl_down(acc, off, 64);
            if (lane == 0)
                out[row] = o[row] * (acc + bv[row] * Gv) / fmaxf(fabsf(Gv), 1.0f);
        }
    }
}

extern "C" void kernel_launch(void* const* d_in, const int* in_sizes, int n_in,
                              void* d_out, int out_size, void* d_ws, size_t ws_size,
                              hipStream_t stream) {
    const float* x  = (const float*)d_in[0];
    const float* Wq = (const float*)d_in[1];  const float* bq = (const float*)d_in[2];
    const float* Wk = (const float*)d_in[3];  const float* bk = (const float*)d_in[4];
    const float* Wv = (const float*)d_in[5];  const float* bv = (const float*)d_in[6];
    const float* Wi = (const float*)d_in[7];  const float* bi = (const float*)d_in[8];
    const float* Wf = (const float*)d_in[9];  const float* bf = (const float*)d_in[10];
    const float* Wo = (const float*)d_in[11]; const float* bo = (const float*)d_in[12];
    const float* cw = (const float*)d_in[13]; const float* cb = (const float*)d_in[14];
    float* out = (float*)d_out;

    float* ws = (float*)d_ws;
    float* xp  = ws;                       // TP*F   = 525056
    float* zk  = xp  + TP * F;             // TP*H   = 787584
    float* ai  = zk  + TP * H;             // TP*H
    float* lf  = ai  + TP * H;             // TP*H
    float* cs  = lf  + TP * H;             // NCS*H  = 98688
    float* co  = cs  + NCS * H;            // NCS*H
    float* qv  = co  + NCS * H;            // H
    float* ov  = qv  + H;                  // H
    float* zf  = ov  + H;                  // F (z accumulator)
    float* Gf  = zf  + F;                  // 1 (zf+256)
    unsigned int* tk = (unsigned int*)(zf + 264);  // ticket (zeroed by D1)

    k1_front<<<610, 256, 0, stream>>>(x, cw, cb, Wq, bq, Wo, bo, xp, qv, ov, zf);
    k2_proj<<<dim3(NT2, 6, 3), 256, 0, stream>>>(xp, Wk, bk, Wi, bi, Wf, bf, zk, ai, lf, cs);
    k3b_scan<<<6, 64, 0, stream>>>(cs, co);
    k3_back<<<NC4, 384, 0, stream>>>(ai, lf, zk, co, qv, xp, zf, Gf, tk, Wv, bv, ov, out);
}

// Round 7
// 140.668 us; speedup vs baseline: 1.6263x; 1.6263x over previous
//
#include <hip/hip_runtime.h>
#include <math.h>

#define T_IN 2048
#define TP   2051   // T+3 conv output length
#define F    256
#define H    384
#define BK   16     // k2 K-tile
#define BT2  32     // k2 t-tile
#define NT2  65     // ceil(TP/32) t-tiles in k2
#define NCS  257    // 8-t chunks (scan length)
#define NC3  257    // k3 chunks of 8

__device__ __forceinline__ float logsig(float z) {
    return (z >= 0.0f) ? -log1pf(__expf(-z)) : z - log1pf(__expf(z));
}

union F4 { float4 v; float f[4]; };

// ---------- D1: conv (blocks 0..512) + q/o GEMV (513..608) + zero (609) ----------
// qo path: xp[TP-1, f] = cb + cw[0]*x[2047, f] exactly (taps t>=2048 are out of
// range), so it needs no conv output -> safe to fuse in the same dispatch.
__global__ __launch_bounds__(256) void k1_front(const float* __restrict__ x,
        const float* __restrict__ cw, const float* __restrict__ cb,
        const float* __restrict__ Wq, const float* __restrict__ bq,
        const float* __restrict__ Wo, const float* __restrict__ bo,
        float* __restrict__ xp, float* __restrict__ q, float* __restrict__ o,
        float* __restrict__ zf) {
    int bid = blockIdx.x;
    int tid = threadIdx.x;
    if (bid < 513) {
        int t = bid * 4 + (tid >> 6);
        int f4 = tid & 63;
        if (t >= TP) return;
        float w[4] = {cw[0], cw[1], cw[2], cw[3]};
        float b = cb[0];
        float4 acc = {b, b, b, b};
        int i0 = t - 3;
        const float4* x4 = (const float4*)x;
        #pragma unroll
        for (int j = 0; j < 4; ++j) {
            int tt = i0 + j;
            if (tt >= 0 && tt < T_IN) {
                float4 xv = x4[tt * 64 + f4];
                acc.x = fmaf(w[j], xv.x, acc.x);
                acc.y = fmaf(w[j], xv.y, acc.y);
                acc.z = fmaf(w[j], xv.z, acc.z);
                acc.w = fmaf(w[j], xv.w, acc.w);
            }
        }
        ((float4*)xp)[t * 64 + f4] = acc;
    } else if (bid < 609) {
        int lane = tid & 63;
        int row = (bid - 513) * 4 + (tid >> 6);
        float w0 = cw[0], b = cb[0];
        float4 xr = ((const float4*)x)[2047 * 64 + lane];
        float4 xv;
        xv.x = fmaf(w0, xr.x, b);
        xv.y = fmaf(w0, xr.y, b);
        xv.z = fmaf(w0, xr.z, b);
        xv.w = fmaf(w0, xr.w, b);
        float4 q4 = *(const float4*)&Wq[row * 256 + lane * 4];
        float4 o4 = *(const float4*)&Wo[row * 256 + lane * 4];
        float aq = fmaf(xv.x, q4.x, fmaf(xv.y, q4.y, fmaf(xv.z, q4.z, xv.w * q4.w)));
        float ao = fmaf(xv.x, o4.x, fmaf(xv.y, o4.y, fmaf(xv.z, o4.z, xv.w * o4.w)));
        #pragma unroll
        for (int off = 32; off; off >>= 1) {
            aq += __shfl_down(aq, off, 64);
            ao += __shfl_down(ao, off, 64);
        }
        if (lane == 0) {
            q[row] = aq + bq[row];
            o[row] = 1.0f / (1.0f + __expf(-(ao + bo[row])));
        }
    } else {
        // zero zf (256) + Gf (at 256) + pad
        for (int i = tid; i < 272; i += 256) zf[i] = 0.0f;
    }
}

// ---------- D2: 32t x 64b x 1 matrix per block, grid (65,6,3) = 1170 blocks ----------
__global__ __launch_bounds__(256) void k2_proj(
    const float* __restrict__ xp,
    const float* __restrict__ Wk, const float* __restrict__ bk,
    const float* __restrict__ Wi, const float* __restrict__ bi,
    const float* __restrict__ Wf, const float* __restrict__ bf,
    float* __restrict__ zk, float* __restrict__ ai, float* __restrict__ lf,
    float* __restrict__ cs) {
    __shared__ float alds[2][BT2][20];    // xp tile [t][k], pad 20 (float4-aligned)
    __shared__ float wlds[2][BK][66];     // W^T [k][b]
    __shared__ float csred[8][66];
    int tid = threadIdx.x;
    int mz = blockIdx.z;
    const float* __restrict__ W    = (mz == 0) ? Wk : (mz == 1) ? Wi : Wf;
    const float* __restrict__ bias = (mz == 0) ? bk : (mz == 1) ? bi : bf;
    int t0 = blockIdx.x * BT2, b0 = blockIdx.y * 64;
    int tx = tid & 31, ty = tid >> 5;
    float2 acc[4];
    #pragma unroll
    for (int u = 0; u < 4; ++u) { acc[u].x = 0.f; acc[u].y = 0.f; }

    int wrow = tid >> 2;          // 0..63 (W row within tile)
    int wk4 = (tid & 3) * 4;      // k quad
    int grow = (b0 + wrow) * 256 + wk4;
    int atq = tid >> 2;           // 0..31 (a row within tile, tid<128 only)
    int arow = (t0 + atq) * 256 + wk4;
    bool aval = (tid < 128) && (t0 + atq < TP);

    float4 aw = {0.f, 0.f, 0.f, 0.f};
    float4 ww;
    // prologue: load tile 0
    if (aval) aw = *(const float4*)&xp[arow];
    ww = *(const float4*)&W[grow];

    for (int i = 0; i < 16; ++i) {
        int buf = i & 1;
        if (tid < 128) *(float4*)&alds[buf][atq][wk4] = aw;
        {
            F4 wu; wu.v = ww;
            #pragma unroll
            for (int j = 0; j < 4; ++j)
                wlds[buf][wk4 + j][wrow] = wu.f[j];
        }
        __syncthreads();
        if (i < 15) {
            int k0 = (i + 1) * BK;
            if (aval) aw = *(const float4*)&xp[arow + k0];
            ww = *(const float4*)&W[grow + k0];
        }
        #pragma unroll
        for (int g = 0; g < 4; ++g) {
            F4 av0, av1, av2, av3;
            av0.v = *(const float4*)&alds[buf][4 * ty + 0][4 * g];
            av1.v = *(const float4*)&alds[buf][4 * ty + 1][4 * g];
            av2.v = *(const float4*)&alds[buf][4 * ty + 2][4 * g];
            av3.v = *(const float4*)&alds[buf][4 * ty + 3][4 * g];
            #pragma unroll
            for (int j = 0; j < 4; ++j) {
                float2 w0 = *(const float2*)&wlds[buf][4 * g + j][2 * tx];
                acc[0].x = fmaf(av0.f[j], w0.x, acc[0].x);
                acc[0].y = fmaf(av0.f[j], w0.y, acc[0].y);
                acc[1].x = fmaf(av1.f[j], w0.x, acc[1].x);
                acc[1].y = fmaf(av1.f[j], w0.y, acc[1].y);
                acc[2].x = fmaf(av2.f[j], w0.x, acc[2].x);
                acc[2].y = fmaf(av2.f[j], w0.y, acc[2].y);
                acc[3].x = fmaf(av3.f[j], w0.x, acc[3].x);
                acc[3].y = fmaf(av3.f[j], w0.y, acc[3].y);
            }
        }
    }
    // epilogue: 4 t-rows per thread, one matrix
    int bA = b0 + 2 * tx;
    float2 b2 = *(const float2*)&bias[bA];
    if (mz == 0) {
        const float sc = 0.05103103630798287f;  // 1/sqrt(384)
        #pragma unroll
        for (int u = 0; u < 4; ++u) {
            int t = t0 + 4 * ty + u;
            if (t < TP) {
                float2 v;
                v.x = (acc[u].x + b2.x) * sc; v.y = (acc[u].y + b2.y) * sc;
                *(float2*)&zk[t * H + bA] = v;
            }
        }
    } else if (mz == 1) {
        #pragma unroll
        for (int u = 0; u < 4; ++u) {
            int t = t0 + 4 * ty + u;
            if (t < TP) {
                float2 v;
                v.x = acc[u].x + b2.x; v.y = acc[u].y + b2.y;
                *(float2*)&ai[t * H + bA] = v;
            }
        }
    } else {
        float2 lsum = {0.f, 0.f};
        #pragma unroll
        for (int u = 0; u < 4; ++u) {
            int t = t0 + 4 * ty + u;
            if (t < TP) {
                float2 l2;
                l2.x = logsig(acc[u].x + b2.x);
                l2.y = logsig(acc[u].y + b2.y);
                *(float2*)&lf[t * H + bA] = l2;
                lsum.x += l2.x; lsum.y += l2.y;
            }
        }
        // per-8t chunk sums: ty pair (2c, 2c+1) covers chunk c
        *(float2*)&csred[ty][2 * tx] = lsum;
        __syncthreads();
        int cl = tid >> 6;       // 0..3 local chunk
        int bb = tid & 63;
        int c = blockIdx.x * 4 + cl;
        if (c < NCS)
            cs[c * H + b0 + bb] = csred[2 * cl][bb] + csred[2 * cl + 1][bb];
    }
}

// ---------- D3: reverse exclusive scan over 257 chunk sums, grid 6x64 ----------
__global__ __launch_bounds__(64) void k3b_scan(const float* __restrict__ cs,
                                               float* __restrict__ co) {
    int b = blockIdx.x * 64 + threadIdx.x;
    float L = 0.0f;
    #pragma unroll 16
    for (int c = NCS - 1; c >= 0; --c) {
        co[c * H + b] = L;
        L += cs[c * H + b];
    }
}

// ---------- D4: fused w -> g -> atomic (z, G). grid NC3 x 384, chunk 8 t ----------
// No fence/ticket epilogue: R5/R6 showed device-scope __threadfence storms cost
// ~80-100us (VALU 0.7%, HBM 0.8%, dur 105-127us). Dispatch boundary is free.
__global__ __launch_bounds__(384) void k3_fused(
    const float* __restrict__ ai, const float* __restrict__ lf,
    const float* __restrict__ zk, const float* __restrict__ co,
    const float* __restrict__ q, const float* __restrict__ xp,
    float* __restrict__ zf, float* __restrict__ Gf) {
    __shared__ float zred[6][256];
    __shared__ float gred[6];
    int tid = threadIdx.x;
    int w = tid >> 6, lane = tid & 63;
    int c = blockIdx.x, ts = c * 8;
    float co0 = co[c * H + tid];
    float qb = q[tid];
    float aiv[8], lfv[8], zkv[8];
    float4 xv[8];
    if (ts + 8 <= TP) {
        #pragma unroll
        for (int u = 0; u < 8; ++u) {
            int idx = (ts + u) * H + tid;
            aiv[u] = ai[idx]; lfv[u] = lf[idx]; zkv[u] = zk[idx];
            xv[u] = *(const float4*)&xp[(ts + u) * 256 + lane * 4];
        }
    } else {
        #pragma unroll
        for (int u = 0; u < 8; ++u) {
            if (ts + u < TP) {
                int idx = (ts + u) * H + tid;
                aiv[u] = ai[idx]; lfv[u] = lf[idx]; zkv[u] = zk[idx];
                xv[u] = *(const float4*)&xp[(ts + u) * 256 + lane * 4];
            } else {
                aiv[u] = -1e30f; lfv[u] = 0.f; zkv[u] = 0.f;
                xv[u].x = xv[u].y = xv[u].z = xv[u].w = 0.f;
            }
        }
    }
    float S = 0.f, gsum = 0.f;
    float z0 = 0.f, z1 = 0.f, z2 = 0.f, z3 = 0.f;
    #pragma unroll
    for (int u = 7; u >= 0; --u) {
        float wv = __expf(aiv[u] + co0 + S) * zkv[u] * qb;
        S += lfv[u];
        float s = wv;
        s += __shfl_xor(s, 1, 64);
        s += __shfl_xor(s, 2, 64);
        s += __shfl_xor(s, 4, 64);
        s += __shfl_xor(s, 8, 64);
        s += __shfl_xor(s, 16, 64);
        s += __shfl_xor(s, 32, 64);
        gsum += s;
        z0 = fmaf(s, xv[u].x, z0);
        z1 = fmaf(s, xv[u].y, z1);
        z2 = fmaf(s, xv[u].z, z2);
        z3 = fmaf(s, xv[u].w, z3);
    }
    zred[w][lane * 4 + 0] = z0;
    zred[w][lane * 4 + 1] = z1;
    zred[w][lane * 4 + 2] = z2;
    zred[w][lane * 4 + 3] = z3;
    if (lane == 0) gred[w] = gsum;
    __syncthreads();
    if (tid < 256) {
        float s = zred[0][tid] + zred[1][tid] + zred[2][tid]
                + zred[3][tid] + zred[4][tid] + zred[5][tid];
        atomicAdd(&zf[tid], s);
    }
    if (tid == 0)
        atomicAdd(Gf, gred[0] + gred[1] + gred[2] + gred[3] + gred[4] + gred[5]);
}

// ---------- D5: wave-per-row GEMV finalize, grid 96 ----------
__global__ __launch_bounds__(256) void k6_out(const float* __restrict__ zf,
        const float* __restrict__ Gf,
        const float* __restrict__ Wv, const float* __restrict__ bv,
        const float* __restrict__ o, float* __restrict__ out) {
    int tid = threadIdx.x;
    int lane = tid & 63;
    int row = blockIdx.x * 4 + (tid >> 6);
    float Gv = Gf[0];
    float4 zv = *(const float4*)&zf[lane * 4];
    float4 wv = *(const float4*)&Wv[row * 256 + lane * 4];
    float acc = fmaf(zv.x, wv.x, fmaf(zv.y, wv.y, fmaf(zv.z, wv.z, zv.w * wv.w)));
    #pragma unroll
    for (int off = 32; off; off >>= 1) acc += __shfl_down(acc, off, 64);
    if (lane == 0)
        out[row] = o[row] * (acc + bv[row] * Gv) / fmaxf(fabsf(Gv), 1.0f);
}

extern "C" void kernel_launch(void* const* d_in, const int* in_sizes, int n_in,
                              void* d_out, int out_size, void* d_ws, size_t ws_size,
                              hipStream_t stream) {
    const float* x  = (const float*)d_in[0];
    const float* Wq = (const float*)d_in[1];  const float* bq = (const float*)d_in[2];
    const float* Wk = (const float*)d_in[3];  const float* bk = (const float*)d_in[4];
    const float* Wv = (const float*)d_in[5];  const float* bv = (const float*)d_in[6];
    const float* Wi = (const float*)d_in[7];  const float* bi = (const float*)d_in[8];
    const float* Wf = (const float*)d_in[9];  const float* bf = (const float*)d_in[10];
    const float* Wo = (const float*)d_in[11]; const float* bo = (const float*)d_in[12];
    const float* cw = (const float*)d_in[13]; const float* cb = (const float*)d_in[14];
    float* out = (float*)d_out;

    float* ws = (float*)d_ws;
    float* xp  = ws;                       // TP*F   = 525056
    float* zk  = xp  + TP * F;             // TP*H   = 787584
    float* ai  = zk  + TP * H;             // TP*H
    float* lf  = ai  + TP * H;             // TP*H
    float* cs  = lf  + TP * H;             // NCS*H  = 98688
    float* co  = cs  + NCS * H;            // NCS*H
    float* qv  = co  + NCS * H;            // H
    float* ov  = qv  + H;                  // H
    float* zf  = ov  + H;                  // F (z accumulator)
    float* Gf  = zf  + F;                  // 1 (zf+256)

    k1_front<<<610, 256, 0, stream>>>(x, cw, cb, Wq, bq, Wo, bo, xp, qv, ov, zf);
    k2_proj<<<dim3(NT2, 6, 3), 256, 0, stream>>>(xp, Wk, bk, Wi, bi, Wf, bf, zk, ai, lf, cs);
    k3b_scan<<<6, 64, 0, stream>>>(cs, co);
    k3_fused<<<NC3, 384, 0, stream>>>(ai, lf, zk, co, qv, xp, zf, Gf);
    k6_out<<<96, 256, 0, stream>>>(zf, Gf, Wv, bv, ov, out);
}